// Round 1
// baseline (477.056 us; speedup 1.0000x reference)
//
#include <hip/hip_runtime.h>
#include <hip/hip_bf16.h>

#define H_DIM 1024
#define I_DIM 2048
#define NE 8
#define NT 4096

typedef __bf16 bf16x8 __attribute__((ext_vector_type(8)));
typedef float f32x4 __attribute__((ext_vector_type(4)));

// 16B-chunk index within a [rows][8-chunk] LDS tile, XOR-swizzled so that
// lanes reading different rows at the same column hit different bank groups.
__device__ __forceinline__ int swzc(int r, int j) { return r * 8 + (j ^ (r & 7)); }

__device__ __forceinline__ bf16x8 cvt8(float4 a, float4 b) {
  bf16x8 r;
  r[0] = (__bf16)a.x; r[1] = (__bf16)a.y; r[2] = (__bf16)a.z; r[3] = (__bf16)a.w;
  r[4] = (__bf16)b.x; r[5] = (__bf16)b.y; r[6] = (__bf16)b.z; r[7] = (__bf16)b.w;
  return r;
}

__global__ __launch_bounds__(256) void k_cast(const float* __restrict__ x,
                                              __bf16* __restrict__ xb) {
  int id = blockIdx.x * 256 + threadIdx.x;           // NT*H/8 total
  const float4* xv = (const float4*)x;
  float4 a = xv[(size_t)id * 2];
  float4 b = xv[(size_t)id * 2 + 1];
  ((bf16x8*)xb)[id] = cvt8(a, b);
}

__global__ __launch_bounds__(256) void k_router(const float* __restrict__ x,
                                                const float* __restrict__ rw,
                                                const float* __restrict__ rbias,
                                                int* __restrict__ counts,
                                                int* __restrict__ list,
                                                int* __restrict__ tE,
                                                int* __restrict__ tP,
                                                float* __restrict__ tG) {
  int wv = threadIdx.x >> 6, lane = threadIdx.x & 63;
  int t = blockIdx.x * 4 + wv;
  float acc[NE];
#pragma unroll
  for (int e = 0; e < NE; e++) acc[e] = 0.f;
  const float4* xr = (const float4*)(x + (size_t)t * H_DIM);
  const float4* wr4 = (const float4*)rw;
#pragma unroll
  for (int it = 0; it < (H_DIM / 4) / 64; ++it) {
    int c = it * 64 + lane;
    float4 xv = xr[c];
#pragma unroll
    for (int e = 0; e < NE; e++) {
      float4 wv = wr4[e * (H_DIM / 4) + c];
      acc[e] += xv.x * wv.x + xv.y * wv.y + xv.z * wv.z + xv.w * wv.w;
    }
  }
#pragma unroll
  for (int e = 0; e < NE; e++) {
#pragma unroll
    for (int off = 32; off > 0; off >>= 1) acc[e] += __shfl_xor(acc[e], off, 64);
  }
  if (lane == 0) {
    float p[NE];
#pragma unroll
    for (int e = 0; e < NE; e++) p[e] = 1.f / (1.f + expf(-(acc[e] + rbias[e])));
    int e0 = 0;
#pragma unroll
    for (int e = 1; e < NE; e++) if (p[e] > p[e0]) e0 = e;
    int e1 = -1;
#pragma unroll
    for (int e = 0; e < NE; e++) if (e != e0 && (e1 < 0 || p[e] > p[e1])) e1 = e;
    float s = p[e0] + p[e1];
    float g0 = p[e0] / s, g1 = p[e1] / s;
    int p0 = atomicAdd(&counts[e0], 1);
    int p1 = atomicAdd(&counts[e1], 1);
    list[e0 * NT + p0] = t;
    list[e1 * NT + p1] = t;
    tE[t * 2] = e0; tE[t * 2 + 1] = e1;
    tP[t * 2] = p0; tP[t * 2 + 1] = p1;
    tG[t * 2] = g0; tG[t * 2 + 1] = g1;
  }
}

__global__ void k_prefix(const int* __restrict__ counts, int* __restrict__ bases) {
  if (threadIdx.x == 0) {
    int s = 0;
    for (int e = 0; e < NE; e++) { bases[e] = s; s += counts[e]; }
  }
}

// Fused gate+up GEMM. Tile 128x64, BK=64, 256 threads (4 waves as 2x2).
// z==NE -> shared expert (dense rows, out hs); z<NE -> routed expert z
// (gathered rows via list, out hr compact rows).
__global__ __launch_bounds__(256) void k_upgate(
    const __bf16* __restrict__ xb, const float* __restrict__ wg,
    const float* __restrict__ wu, const float* __restrict__ sgw,
    const float* __restrict__ suw, const int* __restrict__ counts,
    const int* __restrict__ bases, const int* __restrict__ list,
    __bf16* __restrict__ hs, __bf16* __restrict__ hr) {
  int z = blockIdx.z;
  int m0 = blockIdx.y * 128, n0 = blockIdx.x * 64;
  bool sh = (z == NE);
  int count, base;
  const float *Bg, *Bu;
  if (sh) {
    count = NT; base = 0; Bg = sgw; Bu = suw;
  } else {
    count = counts[z];
    if (m0 >= count) return;
    base = bases[z];
    Bg = wg + (size_t)z * I_DIM * H_DIM;
    Bu = wu + (size_t)z * I_DIM * H_DIM;
  }

  __shared__ bf16x8 sA[128 * 8];
  __shared__ bf16x8 sBg[64 * 8];
  __shared__ bf16x8 sBu[64 * 8];

  int tid = threadIdx.x;
  int rowTok[4];
#pragma unroll
  for (int q = 0; q < 4; q++) {
    int r = (tid + 256 * q) >> 3;
    int gr = m0 + r;
    rowTok[q] = sh ? gr : ((gr < count) ? list[z * NT + gr] : 0);
  }
  int lane = tid & 63, w = tid >> 6, wr = w >> 1, wc = w & 1;
  int fr = lane & 15, fs = lane >> 4;

  f32x4 accg[4][2], accu[4][2];
#pragma unroll
  for (int m = 0; m < 4; m++)
#pragma unroll
    for (int n = 0; n < 2; n++) {
      accg[m][n] = (f32x4){0.f, 0.f, 0.f, 0.f};
      accu[m][n] = (f32x4){0.f, 0.f, 0.f, 0.f};
    }

  const bf16x8* xrow = (const bf16x8*)xb;  // row stride H/8 = 128 chunks

  for (int kt = 0; kt < H_DIM / 64; ++kt) {
#pragma unroll
    for (int q = 0; q < 4; q++) {
      int c = tid + 256 * q, r = c >> 3, j = c & 7;
      sA[swzc(r, j)] = xrow[(size_t)rowTok[q] * (H_DIM / 8) + kt * 8 + j];
    }
#pragma unroll
    for (int q = 0; q < 2; q++) {
      int c = tid + 256 * q, r = c >> 3, j = c & 7;
      const float* pg = Bg + (size_t)(n0 + r) * H_DIM + kt * 64 + j * 8;
      sBg[swzc(r, j)] = cvt8(*(const float4*)pg, *(const float4*)(pg + 4));
      const float* pu = Bu + (size_t)(n0 + r) * H_DIM + kt * 64 + j * 8;
      sBu[swzc(r, j)] = cvt8(*(const float4*)pu, *(const float4*)(pu + 4));
    }
    __syncthreads();
#pragma unroll
    for (int s = 0; s < 2; s++) {
      int j = s * 4 + fs;
      bf16x8 af[4], bg[2], bu[2];
#pragma unroll
      for (int m = 0; m < 4; m++) af[m] = sA[swzc(wr * 64 + m * 16 + fr, j)];
#pragma unroll
      for (int n = 0; n < 2; n++) {
        bg[n] = sBg[swzc(wc * 32 + n * 16 + fr, j)];
        bu[n] = sBu[swzc(wc * 32 + n * 16 + fr, j)];
      }
#pragma unroll
      for (int m = 0; m < 4; m++)
#pragma unroll
        for (int n = 0; n < 2; n++) {
          accg[m][n] = __builtin_amdgcn_mfma_f32_16x16x32_bf16(af[m], bg[n], accg[m][n], 0, 0, 0);
          accu[m][n] = __builtin_amdgcn_mfma_f32_16x16x32_bf16(af[m], bu[n], accu[m][n], 0, 0, 0);
        }
    }
    __syncthreads();
  }

#pragma unroll
  for (int m = 0; m < 4; m++)
#pragma unroll
    for (int n = 0; n < 2; n++)
#pragma unroll
      for (int q = 0; q < 4; q++) {
        int row = wr * 64 + m * 16 + fs * 4 + q;
        int col = n0 + wc * 32 + n * 16 + fr;
        float g = accg[m][n][q], u = accu[m][n][q];
        float h = g * u / (1.f + expf(-g));  // silu(g)*u
        __bf16 hb = (__bf16)h;
        int grow = m0 + row;
        if (sh) hs[(size_t)grow * I_DIM + col] = hb;
        else if (grow < count) hr[(size_t)(base + grow) * I_DIM + col] = hb;
      }
}

// Down GEMM. Tile 128x128, BK=64. z==NE -> shared (A=hs, writes d_out);
// z<NE -> routed (A=hr rows base.., writes compact y rows, gate applied later).
__global__ __launch_bounds__(256) void k_down(
    const __bf16* __restrict__ hs, const __bf16* __restrict__ hr,
    const float* __restrict__ wd, const float* __restrict__ sdw,
    const int* __restrict__ counts, const int* __restrict__ bases,
    float* __restrict__ out, float* __restrict__ y) {
  int z = blockIdx.z;
  int m0 = blockIdx.y * 128, n0 = blockIdx.x * 128;
  bool sh = (z == NE);
  int count, base;
  const float* B;
  const __bf16* A;
  if (sh) {
    count = NT; base = 0; B = sdw; A = hs;
  } else {
    count = counts[z];
    if (m0 >= count) return;
    base = bases[z];
    B = wd + (size_t)z * H_DIM * I_DIM;
    A = hr + (size_t)base * I_DIM;
  }

  __shared__ bf16x8 sA[128 * 8];
  __shared__ bf16x8 sB[128 * 8];
  int tid = threadIdx.x;
  int lane = tid & 63, w = tid >> 6, wr = w >> 1, wc = w & 1;
  int fr = lane & 15, fs = lane >> 4;

  f32x4 acc[4][4];
#pragma unroll
  for (int m = 0; m < 4; m++)
#pragma unroll
    for (int n = 0; n < 4; n++) acc[m][n] = (f32x4){0.f, 0.f, 0.f, 0.f};

  const bf16x8* arow = (const bf16x8*)A;  // row stride I/8 = 256 chunks

  for (int kt = 0; kt < I_DIM / 64; ++kt) {
#pragma unroll
    for (int q = 0; q < 4; q++) {
      int c = tid + 256 * q, r = c >> 3, j = c & 7;
      sA[swzc(r, j)] = arow[(size_t)(m0 + r) * (I_DIM / 8) + kt * 8 + j];
      const float* pb = B + (size_t)(n0 + r) * I_DIM + kt * 64 + j * 8;
      sB[swzc(r, j)] = cvt8(*(const float4*)pb, *(const float4*)(pb + 4));
    }
    __syncthreads();
#pragma unroll
    for (int s = 0; s < 2; s++) {
      int j = s * 4 + fs;
      bf16x8 af[4], bf[4];
#pragma unroll
      for (int m = 0; m < 4; m++) af[m] = sA[swzc(wr * 64 + m * 16 + fr, j)];
#pragma unroll
      for (int n = 0; n < 4; n++) bf[n] = sB[swzc(wc * 64 + n * 16 + fr, j)];
#pragma unroll
      for (int m = 0; m < 4; m++)
#pragma unroll
        for (int n = 0; n < 4; n++)
          acc[m][n] = __builtin_amdgcn_mfma_f32_16x16x32_bf16(af[m], bf[n], acc[m][n], 0, 0, 0);
    }
    __syncthreads();
  }

#pragma unroll
  for (int m = 0; m < 4; m++)
#pragma unroll
    for (int n = 0; n < 4; n++)
#pragma unroll
      for (int q = 0; q < 4; q++) {
        int row = wr * 64 + m * 16 + fs * 4 + q;
        int col = n0 + wc * 64 + n * 16 + fr;
        float v = acc[m][n][q];
        int grow = m0 + row;
        if (sh) out[(size_t)grow * H_DIM + col] = v;
        else if (grow < count) y[(size_t)(base + grow) * H_DIM + col] = v;
      }
}

__global__ __launch_bounds__(256) void k_combine(
    const float* __restrict__ y, const int* __restrict__ bases,
    const int* __restrict__ tE, const int* __restrict__ tP,
    const float* __restrict__ tG, float* __restrict__ out) {
  int t = blockIdx.x;
  int c = threadIdx.x;  // H/4 = 256 float4 per token row
  int e0 = tE[t * 2], e1 = tE[t * 2 + 1];
  int r0 = bases[e0] + tP[t * 2], r1 = bases[e1] + tP[t * 2 + 1];
  float g0 = tG[t * 2], g1 = tG[t * 2 + 1];
  const float4* y4 = (const float4*)y;
  float4* o4 = (float4*)out;
  float4 s = o4[(size_t)t * (H_DIM / 4) + c];
  float4 a = y4[(size_t)r0 * (H_DIM / 4) + c];
  float4 b = y4[(size_t)r1 * (H_DIM / 4) + c];
  s.x += g0 * a.x + g1 * b.x;
  s.y += g0 * a.y + g1 * b.y;
  s.z += g0 * a.z + g1 * b.z;
  s.w += g0 * a.w + g1 * b.w;
  o4[(size_t)t * (H_DIM / 4) + c] = s;
}

extern "C" void kernel_launch(void* const* d_in, const int* in_sizes, int n_in,
                              void* d_out, int out_size, void* d_ws, size_t ws_size,
                              hipStream_t stream) {
  const float* x = (const float*)d_in[0];
  const float* sg_w = (const float*)d_in[1];
  const float* su_w = (const float*)d_in[2];
  const float* sd_w = (const float*)d_in[3];
  const float* router_w = (const float*)d_in[4];
  const float* routing_bias = (const float*)d_in[5];
  const float* wg = (const float*)d_in[6];
  const float* wu = (const float*)d_in[7];
  const float* wd = (const float*)d_in[8];
  float* out = (float*)d_out;
  char* ws = (char*)d_ws;

  __bf16* xb = (__bf16*)(ws + 0);              //  8,388,608 B
  __bf16* hs = (__bf16*)(ws + 8388608);        // 16,777,216 B
  __bf16* hr = (__bf16*)(ws + 25165824);       // 33,554,432 B
  float* y   = (float*)(ws + 58720256);        // 33,554,432 B
  int* counts = (int*)(ws + 92274688);         // 32 B
  int* bases  = (int*)(ws + 92274720);         // 32 B
  int* list   = (int*)(ws + 92274752);         // 131,072 B
  int* tE     = (int*)(ws + 92405824);         // 32,768 B
  int* tP     = (int*)(ws + 92438592);         // 32,768 B
  float* tG   = (float*)(ws + 92471360);       // 32,768 B

  hipMemsetAsync(counts, 0, NE * sizeof(int), stream);
  k_cast<<<(NT * H_DIM / 8) / 256, 256, 0, stream>>>(x, xb);
  k_router<<<NT / 4, 256, 0, stream>>>(x, router_w, routing_bias, counts, list, tE, tP, tG);
  k_prefix<<<1, 64, 0, stream>>>(counts, bases);
  dim3 gu(I_DIM / 64, NT / 128, NE + 1);
  k_upgate<<<gu, 256, 0, stream>>>(xb, wg, wu, sg_w, su_w, counts, bases, list, hs, hr);
  dim3 gd(H_DIM / 128, NT / 128, NE + 1);
  k_down<<<gd, 256, 0, stream>>>(hs, hr, wd, sd_w, counts, bases, out, y);
  k_combine<<<NT, 256, 0, stream>>>(y, bases, tE, tP, tG, out);
}

// Round 2
// 458.674 us; speedup vs baseline: 1.0401x; 1.0401x over previous
//
#include <hip/hip_runtime.h>
#include <hip/hip_bf16.h>

#define H_DIM 1024
#define I_DIM 2048
#define NE 8
#define NT 4096

typedef __bf16 bf16x8 __attribute__((ext_vector_type(8)));
typedef float f32x4 __attribute__((ext_vector_type(4)));

// 16B-chunk index within a [rows][8-chunk] LDS tile, XOR-swizzled so that
// lanes reading different rows at the same column hit different bank groups.
__device__ __forceinline__ int swzc(int r, int j) { return r * 8 + (j ^ (r & 7)); }

__device__ __forceinline__ bf16x8 cvt8(float4 a, float4 b) {
  bf16x8 r;
  r[0] = (__bf16)a.x; r[1] = (__bf16)a.y; r[2] = (__bf16)a.z; r[3] = (__bf16)a.w;
  r[4] = (__bf16)b.x; r[5] = (__bf16)b.y; r[6] = (__bf16)b.z; r[7] = (__bf16)b.w;
  return r;
}

// async global->LDS, 16B per lane. LDS dest must be wave-uniform (HW adds lane*16).
__device__ __forceinline__ void gl16(const void* g, void* l) {
  __builtin_amdgcn_global_load_lds(
      (const __attribute__((address_space(1))) unsigned int*)g,
      (__attribute__((address_space(3))) unsigned int*)l, 16, 0, 0);
}

__global__ __launch_bounds__(256) void k_cast(const float* __restrict__ x,
                                              __bf16* __restrict__ xb) {
  int id = blockIdx.x * 256 + threadIdx.x;           // NT*H/8 total
  const float4* xv = (const float4*)x;
  float4 a = xv[(size_t)id * 2];
  float4 b = xv[(size_t)id * 2 + 1];
  ((bf16x8*)xb)[id] = cvt8(a, b);
}

// generic fp32 -> bf16 cast, 8 elems/thread, grid-stride
__global__ __launch_bounds__(256) void k_castw(const float* __restrict__ s,
                                               __bf16* __restrict__ d, int n8) {
  int stride = gridDim.x * 256;
  const float4* s4 = (const float4*)s;
  for (int i = blockIdx.x * 256 + threadIdx.x; i < n8; i += stride)
    ((bf16x8*)d)[i] = cvt8(s4[(size_t)i * 2], s4[(size_t)i * 2 + 1]);
}

__global__ __launch_bounds__(256) void k_router(const float* __restrict__ x,
                                                const float* __restrict__ rw,
                                                const float* __restrict__ rbias,
                                                int* __restrict__ counts,
                                                int* __restrict__ list,
                                                int* __restrict__ tE,
                                                int* __restrict__ tP,
                                                float* __restrict__ tG) {
  int wv = threadIdx.x >> 6, lane = threadIdx.x & 63;
  int t = blockIdx.x * 4 + wv;
  float acc[NE];
#pragma unroll
  for (int e = 0; e < NE; e++) acc[e] = 0.f;
  const float4* xr = (const float4*)(x + (size_t)t * H_DIM);
  const float4* wr4 = (const float4*)rw;
#pragma unroll
  for (int it = 0; it < (H_DIM / 4) / 64; ++it) {
    int c = it * 64 + lane;
    float4 xv = xr[c];
#pragma unroll
    for (int e = 0; e < NE; e++) {
      float4 wv = wr4[e * (H_DIM / 4) + c];
      acc[e] += xv.x * wv.x + xv.y * wv.y + xv.z * wv.z + xv.w * wv.w;
    }
  }
#pragma unroll
  for (int e = 0; e < NE; e++) {
#pragma unroll
    for (int off = 32; off > 0; off >>= 1) acc[e] += __shfl_xor(acc[e], off, 64);
  }
  if (lane == 0) {
    float p[NE];
#pragma unroll
    for (int e = 0; e < NE; e++) p[e] = 1.f / (1.f + expf(-(acc[e] + rbias[e])));
    int e0 = 0;
#pragma unroll
    for (int e = 1; e < NE; e++) if (p[e] > p[e0]) e0 = e;
    int e1 = -1;
#pragma unroll
    for (int e = 0; e < NE; e++) if (e != e0 && (e1 < 0 || p[e] > p[e1])) e1 = e;
    float s = p[e0] + p[e1];
    float g0 = p[e0] / s, g1 = p[e1] / s;
    int p0 = atomicAdd(&counts[e0], 1);
    int p1 = atomicAdd(&counts[e1], 1);
    list[e0 * NT + p0] = t;
    list[e1 * NT + p1] = t;
    tE[t * 2] = e0; tE[t * 2 + 1] = e1;
    tP[t * 2] = p0; tP[t * 2 + 1] = p1;
    tG[t * 2] = g0; tG[t * 2 + 1] = g1;
  }
}

__global__ void k_prefix(const int* __restrict__ counts, int* __restrict__ bases) {
  if (threadIdx.x == 0) {
    int s = 0;
    for (int e = 0; e < NE; e++) { bases[e] = s; s += counts[e]; }
  }
}

// ---------------- fast path: bf16 weights + global_load_lds staging ----------

// Fused gate+up GEMM. Tile 128x64(cols, both g and u), BK=64, 4 waves (2x2).
__global__ __launch_bounds__(256) void k_upgate2(
    const __bf16* __restrict__ xb, const __bf16* __restrict__ wgb,
    const __bf16* __restrict__ wub, const __bf16* __restrict__ sgb,
    const __bf16* __restrict__ sub, const int* __restrict__ counts,
    const int* __restrict__ bases, const int* __restrict__ list,
    __bf16* __restrict__ hs, __bf16* __restrict__ hr) {
  int z = blockIdx.z;
  int m0 = blockIdx.y * 128, n0 = blockIdx.x * 64;
  bool sh = (z == NE);
  int count, base;
  const __bf16 *Bg, *Bu;
  if (sh) {
    count = NT; base = 0; Bg = sgb; Bu = sub;
  } else {
    count = counts[z];
    if (m0 >= count) return;
    base = bases[z];
    Bg = wgb + (size_t)z * I_DIM * H_DIM;
    Bu = wub + (size_t)z * I_DIM * H_DIM;
  }

  __shared__ bf16x8 sA[128 * 8];   // 16 KB
  __shared__ bf16x8 sBg[64 * 8];   //  8 KB
  __shared__ bf16x8 sBu[64 * 8];   //  8 KB

  int tid = threadIdx.x, lane = tid & 63, w = tid >> 6;
  int wr = w >> 1, wc = w & 1;
  int fr = lane & 15, fs = lane >> 4;

  // Per-lane pre-swizzled global source chunk offsets (LDS dest stays linear;
  // read side applies the same XOR -> conflict-free, content correct).
  size_t srcA[4];
#pragma unroll
  for (int q = 0; q < 4; q++) {
    int C = (w * 4 + q) * 64 + lane;      // linear chunk in sA
    int r = C >> 3, j = C & 7;
    int gr = m0 + r;
    int tok = sh ? gr : ((gr < count) ? list[z * NT + gr] : 0);
    srcA[q] = (size_t)tok * (H_DIM / 8) + (j ^ (r & 7));
  }
  size_t srcB[2];
#pragma unroll
  for (int q = 0; q < 2; q++) {
    int C = (w * 2 + q) * 64 + lane;      // linear chunk in sBg/sBu
    int r = C >> 3, j = C & 7;
    srcB[q] = (size_t)(n0 + r) * (H_DIM / 8) + (j ^ (r & 7));
  }

  f32x4 accg[4][2], accu[4][2];
#pragma unroll
  for (int m = 0; m < 4; m++)
#pragma unroll
    for (int n = 0; n < 2; n++) {
      accg[m][n] = (f32x4){0.f, 0.f, 0.f, 0.f};
      accu[m][n] = (f32x4){0.f, 0.f, 0.f, 0.f};
    }

  const bf16x8* xrow = (const bf16x8*)xb;
  const bf16x8* bg8 = (const bf16x8*)Bg;
  const bf16x8* bu8 = (const bf16x8*)Bu;

  for (int kt = 0; kt < H_DIM / 64; ++kt) {
#pragma unroll
    for (int q = 0; q < 4; q++)
      gl16(xrow + srcA[q] + kt * 8, &sA[(w * 4 + q) * 64]);
#pragma unroll
    for (int q = 0; q < 2; q++) {
      gl16(bg8 + srcB[q] + kt * 8, &sBg[(w * 2 + q) * 64]);
      gl16(bu8 + srcB[q] + kt * 8, &sBu[(w * 2 + q) * 64]);
    }
    __syncthreads();
#pragma unroll
    for (int s = 0; s < 2; s++) {
      int j = s * 4 + fs;
      bf16x8 af[4], bg[2], bu[2];
#pragma unroll
      for (int m = 0; m < 4; m++) af[m] = sA[swzc(wr * 64 + m * 16 + fr, j)];
#pragma unroll
      for (int n = 0; n < 2; n++) {
        bg[n] = sBg[swzc(wc * 32 + n * 16 + fr, j)];
        bu[n] = sBu[swzc(wc * 32 + n * 16 + fr, j)];
      }
#pragma unroll
      for (int m = 0; m < 4; m++)
#pragma unroll
        for (int n = 0; n < 2; n++) {
          accg[m][n] = __builtin_amdgcn_mfma_f32_16x16x32_bf16(af[m], bg[n], accg[m][n], 0, 0, 0);
          accu[m][n] = __builtin_amdgcn_mfma_f32_16x16x32_bf16(af[m], bu[n], accu[m][n], 0, 0, 0);
        }
    }
    __syncthreads();
  }

#pragma unroll
  for (int m = 0; m < 4; m++)
#pragma unroll
    for (int n = 0; n < 2; n++)
#pragma unroll
      for (int q = 0; q < 4; q++) {
        int row = wr * 64 + m * 16 + fs * 4 + q;
        int col = n0 + wc * 32 + n * 16 + fr;
        float g = accg[m][n][q], u = accu[m][n][q];
        float h = g * u / (1.f + expf(-g));  // silu(g)*u
        __bf16 hb = (__bf16)h;
        int grow = m0 + row;
        if (sh) hs[(size_t)grow * I_DIM + col] = hb;
        else if (grow < count) hr[(size_t)(base + grow) * I_DIM + col] = hb;
      }
}

// Down GEMM. Tile 128x128, BK=64, bf16 A and bf16 weights.
__global__ __launch_bounds__(256) void k_down2(
    const __bf16* __restrict__ hs, const __bf16* __restrict__ hr,
    const __bf16* __restrict__ wdb, const __bf16* __restrict__ sdb,
    const int* __restrict__ counts, const int* __restrict__ bases,
    float* __restrict__ out, float* __restrict__ y) {
  int z = blockIdx.z;
  int m0 = blockIdx.y * 128, n0 = blockIdx.x * 128;
  bool sh = (z == NE);
  int count, base;
  const __bf16* B;
  const __bf16* A;
  if (sh) {
    count = NT; base = 0; B = sdb; A = hs;
  } else {
    count = counts[z];
    if (m0 >= count) return;
    base = bases[z];
    B = wdb + (size_t)z * H_DIM * I_DIM;
    A = hr + (size_t)base * I_DIM;
  }

  __shared__ bf16x8 sA[128 * 8];   // 16 KB
  __shared__ bf16x8 sB[128 * 8];   // 16 KB

  int tid = threadIdx.x, lane = tid & 63, w = tid >> 6;
  int wr = w >> 1, wc = w & 1;
  int fr = lane & 15, fs = lane >> 4;

  size_t srcA[4], srcB[4];
#pragma unroll
  for (int q = 0; q < 4; q++) {
    int C = (w * 4 + q) * 64 + lane;
    int r = C >> 3, j = C & 7;
    int ra = m0 + r; if (ra > count - 1) ra = count - 1;   // stay in valid rows
    srcA[q] = (size_t)ra * (I_DIM / 8) + (j ^ (r & 7));
    srcB[q] = (size_t)(n0 + r) * (I_DIM / 8) + (j ^ (r & 7));
  }

  f32x4 acc[4][4];
#pragma unroll
  for (int m = 0; m < 4; m++)
#pragma unroll
    for (int n = 0; n < 4; n++) acc[m][n] = (f32x4){0.f, 0.f, 0.f, 0.f};

  const bf16x8* a8 = (const bf16x8*)A;
  const bf16x8* b8 = (const bf16x8*)B;

  for (int kt = 0; kt < I_DIM / 64; ++kt) {
#pragma unroll
    for (int q = 0; q < 4; q++) {
      gl16(a8 + srcA[q] + kt * 8, &sA[(w * 4 + q) * 64]);
      gl16(b8 + srcB[q] + kt * 8, &sB[(w * 4 + q) * 64]);
    }
    __syncthreads();
#pragma unroll
    for (int s = 0; s < 2; s++) {
      int j = s * 4 + fs;
      bf16x8 af[4], bf[4];
#pragma unroll
      for (int m = 0; m < 4; m++) af[m] = sA[swzc(wr * 64 + m * 16 + fr, j)];
#pragma unroll
      for (int n = 0; n < 4; n++) bf[n] = sB[swzc(wc * 64 + n * 16 + fr, j)];
#pragma unroll
      for (int m = 0; m < 4; m++)
#pragma unroll
        for (int n = 0; n < 4; n++)
          acc[m][n] = __builtin_amdgcn_mfma_f32_16x16x32_bf16(af[m], bf[n], acc[m][n], 0, 0, 0);
    }
    __syncthreads();
  }

#pragma unroll
  for (int m = 0; m < 4; m++)
#pragma unroll
    for (int n = 0; n < 4; n++)
#pragma unroll
      for (int q = 0; q < 4; q++) {
        int row = wr * 64 + m * 16 + fs * 4 + q;
        int col = n0 + wc * 64 + n * 16 + fr;
        float v = acc[m][n][q];
        int grow = m0 + row;
        if (sh) out[(size_t)grow * H_DIM + col] = v;
        else if (grow < count) y[(size_t)(base + grow) * H_DIM + col] = v;
      }
}

// ---------------- fallback path (round-1 kernels, fp32 weights) --------------

__global__ __launch_bounds__(256) void k_upgate_f32(
    const __bf16* __restrict__ xb, const float* __restrict__ wg,
    const float* __restrict__ wu, const float* __restrict__ sgw,
    const float* __restrict__ suw, const int* __restrict__ counts,
    const int* __restrict__ bases, const int* __restrict__ list,
    __bf16* __restrict__ hs, __bf16* __restrict__ hr) {
  int z = blockIdx.z;
  int m0 = blockIdx.y * 128, n0 = blockIdx.x * 64;
  bool sh = (z == NE);
  int count, base;
  const float *Bg, *Bu;
  if (sh) { count = NT; base = 0; Bg = sgw; Bu = suw; }
  else {
    count = counts[z];
    if (m0 >= count) return;
    base = bases[z];
    Bg = wg + (size_t)z * I_DIM * H_DIM;
    Bu = wu + (size_t)z * I_DIM * H_DIM;
  }
  __shared__ bf16x8 sA[128 * 8];
  __shared__ bf16x8 sBg[64 * 8];
  __shared__ bf16x8 sBu[64 * 8];
  int tid = threadIdx.x;
  int rowTok[4];
#pragma unroll
  for (int q = 0; q < 4; q++) {
    int r = (tid + 256 * q) >> 3;
    int gr = m0 + r;
    rowTok[q] = sh ? gr : ((gr < count) ? list[z * NT + gr] : 0);
  }
  int lane = tid & 63, w = tid >> 6, wr = w >> 1, wc = w & 1;
  int fr = lane & 15, fs = lane >> 4;
  f32x4 accg[4][2], accu[4][2];
#pragma unroll
  for (int m = 0; m < 4; m++)
#pragma unroll
    for (int n = 0; n < 2; n++) {
      accg[m][n] = (f32x4){0.f, 0.f, 0.f, 0.f};
      accu[m][n] = (f32x4){0.f, 0.f, 0.f, 0.f};
    }
  const bf16x8* xrow = (const bf16x8*)xb;
  for (int kt = 0; kt < H_DIM / 64; ++kt) {
#pragma unroll
    for (int q = 0; q < 4; q++) {
      int c = tid + 256 * q, r = c >> 3, j = c & 7;
      sA[swzc(r, j)] = xrow[(size_t)rowTok[q] * (H_DIM / 8) + kt * 8 + j];
    }
#pragma unroll
    for (int q = 0; q < 2; q++) {
      int c = tid + 256 * q, r = c >> 3, j = c & 7;
      const float* pg = Bg + (size_t)(n0 + r) * H_DIM + kt * 64 + j * 8;
      sBg[swzc(r, j)] = cvt8(*(const float4*)pg, *(const float4*)(pg + 4));
      const float* pu = Bu + (size_t)(n0 + r) * H_DIM + kt * 64 + j * 8;
      sBu[swzc(r, j)] = cvt8(*(const float4*)pu, *(const float4*)(pu + 4));
    }
    __syncthreads();
#pragma unroll
    for (int s = 0; s < 2; s++) {
      int j = s * 4 + fs;
      bf16x8 af[4], bg[2], bu[2];
#pragma unroll
      for (int m = 0; m < 4; m++) af[m] = sA[swzc(wr * 64 + m * 16 + fr, j)];
#pragma unroll
      for (int n = 0; n < 2; n++) {
        bg[n] = sBg[swzc(wc * 32 + n * 16 + fr, j)];
        bu[n] = sBu[swzc(wc * 32 + n * 16 + fr, j)];
      }
#pragma unroll
      for (int m = 0; m < 4; m++)
#pragma unroll
        for (int n = 0; n < 2; n++) {
          accg[m][n] = __builtin_amdgcn_mfma_f32_16x16x32_bf16(af[m], bg[n], accg[m][n], 0, 0, 0);
          accu[m][n] = __builtin_amdgcn_mfma_f32_16x16x32_bf16(af[m], bu[n], accu[m][n], 0, 0, 0);
        }
    }
    __syncthreads();
  }
#pragma unroll
  for (int m = 0; m < 4; m++)
#pragma unroll
    for (int n = 0; n < 2; n++)
#pragma unroll
      for (int q = 0; q < 4; q++) {
        int row = wr * 64 + m * 16 + fs * 4 + q;
        int col = n0 + wc * 32 + n * 16 + fr;
        float g = accg[m][n][q], u = accu[m][n][q];
        float h = g * u / (1.f + expf(-g));
        __bf16 hb = (__bf16)h;
        int grow = m0 + row;
        if (sh) hs[(size_t)grow * I_DIM + col] = hb;
        else if (grow < count) hr[(size_t)(base + grow) * I_DIM + col] = hb;
      }
}

__global__ __launch_bounds__(256) void k_down_f32(
    const __bf16* __restrict__ hs, const __bf16* __restrict__ hr,
    const float* __restrict__ wd, const float* __restrict__ sdw,
    const int* __restrict__ counts, const int* __restrict__ bases,
    float* __restrict__ out, float* __restrict__ y) {
  int z = blockIdx.z;
  int m0 = blockIdx.y * 128, n0 = blockIdx.x * 128;
  bool sh = (z == NE);
  int count, base;
  const float* B;
  const __bf16* A;
  if (sh) { count = NT; base = 0; B = sdw; A = hs; }
  else {
    count = counts[z];
    if (m0 >= count) return;
    base = bases[z];
    B = wd + (size_t)z * H_DIM * I_DIM;
    A = hr + (size_t)base * I_DIM;
  }
  __shared__ bf16x8 sA[128 * 8];
  __shared__ bf16x8 sB[128 * 8];
  int tid = threadIdx.x;
  int lane = tid & 63, w = tid >> 6, wr = w >> 1, wc = w & 1;
  int fr = lane & 15, fs = lane >> 4;
  f32x4 acc[4][4];
#pragma unroll
  for (int m = 0; m < 4; m++)
#pragma unroll
    for (int n = 0; n < 4; n++) acc[m][n] = (f32x4){0.f, 0.f, 0.f, 0.f};
  const bf16x8* arow = (const bf16x8*)A;
  for (int kt = 0; kt < I_DIM / 64; ++kt) {
#pragma unroll
    for (int q = 0; q < 4; q++) {
      int c = tid + 256 * q, r = c >> 3, j = c & 7;
      sA[swzc(r, j)] = arow[(size_t)(m0 + r) * (I_DIM / 8) + kt * 8 + j];
      const float* pb = B + (size_t)(n0 + r) * I_DIM + kt * 64 + j * 8;
      sB[swzc(r, j)] = cvt8(*(const float4*)pb, *(const float4*)(pb + 4));
    }
    __syncthreads();
#pragma unroll
    for (int s = 0; s < 2; s++) {
      int j = s * 4 + fs;
      bf16x8 af[4], bf[4];
#pragma unroll
      for (int m = 0; m < 4; m++) af[m] = sA[swzc(wr * 64 + m * 16 + fr, j)];
#pragma unroll
      for (int n = 0; n < 4; n++) bf[n] = sB[swzc(wc * 64 + n * 16 + fr, j)];
#pragma unroll
      for (int m = 0; m < 4; m++)
#pragma unroll
        for (int n = 0; n < 4; n++)
          acc[m][n] = __builtin_amdgcn_mfma_f32_16x16x32_bf16(af[m], bf[n], acc[m][n], 0, 0, 0);
    }
    __syncthreads();
  }
#pragma unroll
  for (int m = 0; m < 4; m++)
#pragma unroll
    for (int n = 0; n < 4; n++)
#pragma unroll
      for (int q = 0; q < 4; q++) {
        int row = wr * 64 + m * 16 + fs * 4 + q;
        int col = n0 + wc * 64 + n * 16 + fr;
        float v = acc[m][n][q];
        int grow = m0 + row;
        if (sh) out[(size_t)grow * H_DIM + col] = v;
        else if (grow < count) y[(size_t)(base + grow) * H_DIM + col] = v;
      }
}

__global__ __launch_bounds__(256) void k_combine(
    const float* __restrict__ y, const int* __restrict__ bases,
    const int* __restrict__ tE, const int* __restrict__ tP,
    const float* __restrict__ tG, float* __restrict__ out) {
  int t = blockIdx.x;
  int c = threadIdx.x;  // H/4 = 256 float4 per token row
  int e0 = tE[t * 2], e1 = tE[t * 2 + 1];
  int r0 = bases[e0] + tP[t * 2], r1 = bases[e1] + tP[t * 2 + 1];
  float g0 = tG[t * 2], g1 = tG[t * 2 + 1];
  const float4* y4 = (const float4*)y;
  float4* o4 = (float4*)out;
  float4 s = o4[(size_t)t * (H_DIM / 4) + c];
  float4 a = y4[(size_t)r0 * (H_DIM / 4) + c];
  float4 b = y4[(size_t)r1 * (H_DIM / 4) + c];
  s.x += g0 * a.x + g1 * b.x;
  s.y += g0 * a.y + g1 * b.y;
  s.z += g0 * a.z + g1 * b.z;
  s.w += g0 * a.w + g1 * b.w;
  o4[(size_t)t * (H_DIM / 4) + c] = s;
}

extern "C" void kernel_launch(void* const* d_in, const int* in_sizes, int n_in,
                              void* d_out, int out_size, void* d_ws, size_t ws_size,
                              hipStream_t stream) {
  const float* x = (const float*)d_in[0];
  const float* sg_w = (const float*)d_in[1];
  const float* su_w = (const float*)d_in[2];
  const float* sd_w = (const float*)d_in[3];
  const float* router_w = (const float*)d_in[4];
  const float* routing_bias = (const float*)d_in[5];
  const float* wg = (const float*)d_in[6];
  const float* wu = (const float*)d_in[7];
  const float* wd = (const float*)d_in[8];
  float* out = (float*)d_out;
  char* ws = (char*)d_ws;

  const size_t NEED_FULL = 205750528ull;  // ~196.2 MB

  if (ws_size >= NEED_FULL) {
    // ---- fast path layout ----
    __bf16* xb  = (__bf16*)(ws + 0);            //  8,388,608
    __bf16* hs  = (__bf16*)(ws + 8388608);      // 16,777,216
    __bf16* hr  = (__bf16*)(ws + 25165824);     // 33,554,432
    float*  y   = (float*)(ws + 58720256);      // 33,554,432
    __bf16* wgb = (__bf16*)(ws + 92274688);     // 33,554,432
    __bf16* wub = (__bf16*)(ws + 125829120);    // 33,554,432
    __bf16* wdb = (__bf16*)(ws + 159383552);    // 33,554,432
    __bf16* sgb = (__bf16*)(ws + 192937984);    //  4,194,304
    __bf16* sub = (__bf16*)(ws + 197132288);    //  4,194,304
    __bf16* sdb = (__bf16*)(ws + 201326592);    //  4,194,304
    int* counts = (int*)(ws + 205520896);
    int* bases  = (int*)(ws + 205520928);
    int* list   = (int*)(ws + 205520960);       // 131,072
    int* tE     = (int*)(ws + 205652032);       // 32,768
    int* tP     = (int*)(ws + 205684800);       // 32,768
    float* tG   = (float*)(ws + 205717568);     // 32,768

    hipMemsetAsync(counts, 0, NE * sizeof(int), stream);
    k_cast<<<(NT * H_DIM / 8) / 256, 256, 0, stream>>>(x, xb);
    k_castw<<<2048, 256, 0, stream>>>(wg, wgb, NE * I_DIM * H_DIM / 8);
    k_castw<<<2048, 256, 0, stream>>>(wu, wub, NE * I_DIM * H_DIM / 8);
    k_castw<<<2048, 256, 0, stream>>>(wd, wdb, NE * H_DIM * I_DIM / 8);
    k_castw<<<1024, 256, 0, stream>>>(sg_w, sgb, I_DIM * H_DIM / 8);
    k_castw<<<1024, 256, 0, stream>>>(su_w, sub, I_DIM * H_DIM / 8);
    k_castw<<<1024, 256, 0, stream>>>(sd_w, sdb, H_DIM * I_DIM / 8);
    k_router<<<NT / 4, 256, 0, stream>>>(x, router_w, routing_bias, counts, list, tE, tP, tG);
    k_prefix<<<1, 64, 0, stream>>>(counts, bases);
    dim3 gu(I_DIM / 64, NT / 128, NE + 1);
    k_upgate2<<<gu, 256, 0, stream>>>(xb, wgb, wub, sgb, sub, counts, bases, list, hs, hr);
    dim3 gd(H_DIM / 128, NT / 128, NE + 1);
    k_down2<<<gd, 256, 0, stream>>>(hs, hr, wdb, sdb, counts, bases, out, y);
    k_combine<<<NT, 256, 0, stream>>>(y, bases, tE, tP, tG, out);
  } else {
    // ---- fallback: round-1 structure ----
    __bf16* xb = (__bf16*)(ws + 0);
    __bf16* hs = (__bf16*)(ws + 8388608);
    __bf16* hr = (__bf16*)(ws + 25165824);
    float* y   = (float*)(ws + 58720256);
    int* counts = (int*)(ws + 92274688);
    int* bases  = (int*)(ws + 92274720);
    int* list   = (int*)(ws + 92274752);
    int* tE     = (int*)(ws + 92405824);
    int* tP     = (int*)(ws + 92438592);
    float* tG   = (float*)(ws + 92471360);

    hipMemsetAsync(counts, 0, NE * sizeof(int), stream);
    k_cast<<<(NT * H_DIM / 8) / 256, 256, 0, stream>>>(x, xb);
    k_router<<<NT / 4, 256, 0, stream>>>(x, router_w, routing_bias, counts, list, tE, tP, tG);
    k_prefix<<<1, 64, 0, stream>>>(counts, bases);
    dim3 gu(I_DIM / 64, NT / 128, NE + 1);
    k_upgate_f32<<<gu, 256, 0, stream>>>(xb, wg, wu, sg_w, su_w, counts, bases, list, hs, hr);
    dim3 gd(H_DIM / 128, NT / 128, NE + 1);
    k_down_f32<<<gd, 256, 0, stream>>>(hs, hr, wd, sd_w, counts, bases, out, y);
    k_combine<<<NT, 256, 0, stream>>>(y, bases, tE, tP, tG, out);
  }
}

// Round 3
// 422.046 us; speedup vs baseline: 1.1303x; 1.0868x over previous
//
#include <hip/hip_runtime.h>
#include <hip/hip_bf16.h>

#define H_DIM 1024
#define I_DIM 2048
#define NE 8
#define NT 4096

typedef __bf16 bf16x8 __attribute__((ext_vector_type(8)));
typedef __bf16 bf16x4 __attribute__((ext_vector_type(4)));
typedef float f32x4 __attribute__((ext_vector_type(4)));

// 16B-chunk index within a [rows][8-chunk] LDS tile, XOR-swizzled so lanes
// reading different rows at the same k-chunk hit different bank groups.
__device__ __forceinline__ int swzc(int r, int j) { return r * 8 + (j ^ (r & 7)); }

__device__ __forceinline__ bf16x8 cvt8(float4 a, float4 b) {
  bf16x8 r;
  r[0] = (__bf16)a.x; r[1] = (__bf16)a.y; r[2] = (__bf16)a.z; r[3] = (__bf16)a.w;
  r[4] = (__bf16)b.x; r[5] = (__bf16)b.y; r[6] = (__bf16)b.z; r[7] = (__bf16)b.w;
  return r;
}

// async global->LDS, 16B per lane. LDS dest is wave-uniform base (HW adds lane*16).
__device__ __forceinline__ void gl16(const void* g, void* l) {
  __builtin_amdgcn_global_load_lds(
      (const __attribute__((address_space(1))) unsigned int*)g,
      (__attribute__((address_space(3))) unsigned int*)l, 16, 0, 0);
}

// One-shot cast of all six weight matrices fp32->bf16. All sizes are pow2:
// routed matrices 2^21 chunks each, shared 2^18 chunks each (chunk = 8 elems).
__global__ __launch_bounds__(256) void k_castall(
    const float* __restrict__ wg, const float* __restrict__ wu,
    const float* __restrict__ wd, const float* __restrict__ sg,
    const float* __restrict__ su, const float* __restrict__ sd,
    __bf16* __restrict__ wgb, __bf16* __restrict__ wub, __bf16* __restrict__ wdb,
    __bf16* __restrict__ sgb, __bf16* __restrict__ sub, __bf16* __restrict__ sdb) {
  long long i = (long long)blockIdx.x * 256 + threadIdx.x;
  const long long NW = 1LL << 21, NS = 1LL << 18;
  const float* s; __bf16* d; int off;
  if (i < 3 * NW) {
    int r = (int)(i >> 21); off = (int)(i & (NW - 1));
    s = (r == 0) ? wg : (r == 1) ? wu : wd;
    d = (r == 0) ? wgb : (r == 1) ? wub : wdb;
  } else {
    long long j = i - 3 * NW;
    int r = (int)(j >> 18); off = (int)(j & (NS - 1));
    s = (r == 0) ? sg : (r == 1) ? su : sd;
    d = (r == 0) ? sgb : (r == 1) ? sub : sdb;
  }
  const float4* s4 = (const float4*)s;
  float4 a = s4[(size_t)off * 2], b = s4[(size_t)off * 2 + 1];
  ((bf16x8*)d)[off] = cvt8(a, b);
}

// Router: sigmoid top-2 renorm + per-expert token lists. Also casts x -> xb
// (each wave reads its token's full row anyway).
__global__ __launch_bounds__(256) void k_router(const float* __restrict__ x,
                                                const float* __restrict__ rw,
                                                const float* __restrict__ rbias,
                                                __bf16* __restrict__ xb,
                                                int* __restrict__ counts,
                                                int* __restrict__ list,
                                                int* __restrict__ tE,
                                                int* __restrict__ tP,
                                                float* __restrict__ tG) {
  int wv = threadIdx.x >> 6, lane = threadIdx.x & 63;
  int t = blockIdx.x * 4 + wv;
  float acc[NE];
#pragma unroll
  for (int e = 0; e < NE; e++) acc[e] = 0.f;
  const float4* xr = (const float4*)(x + (size_t)t * H_DIM);
  const float4* wr4 = (const float4*)rw;
  bf16x4* xo = (bf16x4*)xb + (size_t)t * (H_DIM / 4);
#pragma unroll
  for (int it = 0; it < 4; ++it) {
    int c = it * 64 + lane;
    float4 xv = xr[c];
    bf16x4 bv;
    bv[0] = (__bf16)xv.x; bv[1] = (__bf16)xv.y;
    bv[2] = (__bf16)xv.z; bv[3] = (__bf16)xv.w;
    xo[c] = bv;
#pragma unroll
    for (int e = 0; e < NE; e++) {
      float4 wv = wr4[e * (H_DIM / 4) + c];
      acc[e] += xv.x * wv.x + xv.y * wv.y + xv.z * wv.z + xv.w * wv.w;
    }
  }
#pragma unroll
  for (int e = 0; e < NE; e++) {
#pragma unroll
    for (int off = 32; off > 0; off >>= 1) acc[e] += __shfl_xor(acc[e], off, 64);
  }
  if (lane == 0) {
    float p[NE];
#pragma unroll
    for (int e = 0; e < NE; e++) p[e] = 1.f / (1.f + expf(-(acc[e] + rbias[e])));
    int e0 = 0;
#pragma unroll
    for (int e = 1; e < NE; e++) if (p[e] > p[e0]) e0 = e;
    int e1 = -1;
#pragma unroll
    for (int e = 0; e < NE; e++) if (e != e0 && (e1 < 0 || p[e] > p[e1])) e1 = e;
    float s = p[e0] + p[e1];
    float g0 = p[e0] / s, g1 = p[e1] / s;
    int p0 = atomicAdd(&counts[e0], 1);
    int p1 = atomicAdd(&counts[e1], 1);
    list[e0 * NT + p0] = t;
    list[e1 * NT + p1] = t;
    tE[t * 2] = e0; tE[t * 2 + 1] = e1;
    tP[t * 2] = p0; tP[t * 2 + 1] = p1;
    tG[t * 2] = g0; tG[t * 2 + 1] = g1;
  }
}

__global__ void k_prefix(const int* __restrict__ counts, int* __restrict__ bases) {
  if (threadIdx.x == 0) {
    int s = 0;
    for (int e = 0; e < NE; e++) { bases[e] = s; s += counts[e]; }
  }
}

// ---------------------------------------------------------------------------
// Fused gate+up GEMM, 8-wave deep-pipelined. Tile: 256 rows x 128 cols (dual
// g/u accumulators), BK=64, 512 threads (waves 2M x 4N). LDS 128 KB dbuf.
// Per K-tile: 4 phases, each {4 ds_read_b128 A-frags (+8 B-frags at p0) |
// issue 2 prefetch gl16 for tile kt+1 | 16 MFMA under setprio}. One
// __syncthreads per K-tile (its vmcnt(0) drain lands the prefetch).
// ---------------------------------------------------------------------------
__global__ __launch_bounds__(512, 2) void k_upgate8(
    const __bf16* __restrict__ xb, const __bf16* __restrict__ wgb,
    const __bf16* __restrict__ wub, const __bf16* __restrict__ sgb,
    const __bf16* __restrict__ sub, const int* __restrict__ counts,
    const int* __restrict__ bases, const int* __restrict__ list,
    __bf16* __restrict__ hs, __bf16* __restrict__ hr) {
  int z = blockIdx.z;
  int m0 = blockIdx.y * 256, n0 = blockIdx.x * 128;
  bool sh = (z == NE);
  int count, base;
  const __bf16 *Bg, *Bu;
  if (sh) {
    count = NT; base = 0; Bg = sgb; Bu = sub;
  } else {
    count = counts[z];
    if (m0 >= count) return;
    base = bases[z];
    Bg = wgb + (size_t)z * (I_DIM * H_DIM);
    Bu = wub + (size_t)z * (I_DIM * H_DIM);
  }

  __shared__ bf16x8 lds[8192];              // 128 KB
  bf16x8* sA  = lds;                        // [2][2048]  A: 256 rows x 8 chunks
  bf16x8* sBg = lds + 4096;                 // [2][1024]  Bg: 128 x 8
  bf16x8* sBu = lds + 6144;                 // [2][1024]

  int tid = threadIdx.x, lane = tid & 63, w = tid >> 6;
  int wm = w >> 2, wn = w & 3;
  int fr = lane & 15, fs = lane >> 4;

  // stage source chunk offsets (pre-swizzled so linear-LDS content matches
  // the swizzled read pattern)
  int srcA[4], srcB[2];
#pragma unroll
  for (int q = 0; q < 4; q++) {
    int c = q * 512 + tid;
    int r = c >> 3, j = (c & 7) ^ (r & 7);
    int gr = m0 + r;
    int tok = sh ? gr : ((gr < count) ? list[z * NT + gr] : list[z * NT]);
    srcA[q] = tok * (H_DIM / 8) + j;
  }
#pragma unroll
  for (int q = 0; q < 2; q++) {
    int c = q * 512 + tid;
    int r = c >> 3, j = (c & 7) ^ (r & 7);
    srcB[q] = (n0 + r) * (H_DIM / 8) + j;
  }

  const bf16x8* a8 = (const bf16x8*)xb;
  const bf16x8* g8 = (const bf16x8*)Bg;
  const bf16x8* u8 = (const bf16x8*)Bu;

  f32x4 accg[8][2], accu[8][2];
#pragma unroll
  for (int m = 0; m < 8; m++)
#pragma unroll
    for (int n = 0; n < 2; n++) {
      accg[m][n] = (f32x4){0.f, 0.f, 0.f, 0.f};
      accu[m][n] = (f32x4){0.f, 0.f, 0.f, 0.f};
    }

  // prologue: stage K-tile 0 into buffer 0
#pragma unroll
  for (int q = 0; q < 4; q++) gl16(a8 + srcA[q], sA + q * 512 + w * 64);
#pragma unroll
  for (int q = 0; q < 2; q++) {
    gl16(g8 + srcB[q], sBg + q * 512 + w * 64);
    gl16(u8 + srcB[q], sBu + q * 512 + w * 64);
  }
  __syncthreads();

  for (int kt = 0; kt < H_DIM / 64; ++kt) {
    int cur = kt & 1, nxt = cur ^ 1;
    const bf16x8* A = sA + cur * 2048;
    const bf16x8* G = sBg + cur * 1024;
    const bf16x8* U = sBu + cur * 1024;
    bf16x8* dA = sA + nxt * 2048;
    bf16x8* dG = sBg + nxt * 1024;
    bf16x8* dU = sBu + nxt * 1024;
    bool pf = (kt + 1 < H_DIM / 64);
    int ko = (kt + 1) * 8;

    bf16x8 bg[2][2], bu[2][2];
#pragma unroll
    for (int p = 0; p < 4; ++p) {
      bf16x8 af[2][2];
#pragma unroll
      for (int m2 = 0; m2 < 2; m2++)
#pragma unroll
        for (int ks = 0; ks < 2; ks++)
          af[m2][ks] = A[swzc(wm * 128 + (p * 2 + m2) * 16 + fr, ks * 4 + fs)];
      if (p == 0) {
#pragma unroll
        for (int n = 0; n < 2; n++)
#pragma unroll
          for (int ks = 0; ks < 2; ks++) {
            bg[n][ks] = G[swzc(wn * 32 + n * 16 + fr, ks * 4 + fs)];
            bu[n][ks] = U[swzc(wn * 32 + n * 16 + fr, ks * 4 + fs)];
          }
      }
      if (pf) {
        if (p == 0) {
          gl16(a8 + srcA[0] + ko, dA + 0 * 512 + w * 64);
          gl16(a8 + srcA[1] + ko, dA + 1 * 512 + w * 64);
        } else if (p == 1) {
          gl16(a8 + srcA[2] + ko, dA + 2 * 512 + w * 64);
          gl16(a8 + srcA[3] + ko, dA + 3 * 512 + w * 64);
        } else if (p == 2) {
          gl16(g8 + srcB[0] + ko, dG + 0 * 512 + w * 64);
          gl16(g8 + srcB[1] + ko, dG + 1 * 512 + w * 64);
        } else {
          gl16(u8 + srcB[0] + ko, dU + 0 * 512 + w * 64);
          gl16(u8 + srcB[1] + ko, dU + 1 * 512 + w * 64);
        }
      }
      __builtin_amdgcn_s_setprio(1);
#pragma unroll
      for (int m2 = 0; m2 < 2; m2++)
#pragma unroll
        for (int n = 0; n < 2; n++)
#pragma unroll
          for (int ks = 0; ks < 2; ks++) {
            int m = p * 2 + m2;
            accg[m][n] = __builtin_amdgcn_mfma_f32_16x16x32_bf16(af[m2][ks], bg[n][ks], accg[m][n], 0, 0, 0);
            accu[m][n] = __builtin_amdgcn_mfma_f32_16x16x32_bf16(af[m2][ks], bu[n][ks], accu[m][n], 0, 0, 0);
          }
      __builtin_amdgcn_s_setprio(0);
    }
    __syncthreads();
  }

#pragma unroll
  for (int m = 0; m < 8; m++)
#pragma unroll
    for (int n = 0; n < 2; n++)
#pragma unroll
      for (int q2 = 0; q2 < 4; q2++) {
        int row = wm * 128 + m * 16 + fs * 4 + q2;
        int col = n0 + wn * 32 + n * 16 + fr;
        float g = accg[m][n][q2], u = accu[m][n][q2];
        float h = g * u / (1.f + expf(-g));  // silu(g)*u
        __bf16 hb = (__bf16)h;
        int grow = m0 + row;
        if (sh) hs[(size_t)grow * I_DIM + col] = hb;
        else if (grow < count) hr[(size_t)(base + grow) * I_DIM + col] = hb;
      }
}

// Down GEMM, same pipeline. Tile 256x256, BK=64, 8 waves (2M x 4N; wave =
// 128 rows x 64 cols).
__global__ __launch_bounds__(512, 2) void k_down8(
    const __bf16* __restrict__ hs, const __bf16* __restrict__ hr,
    const __bf16* __restrict__ wdb, const __bf16* __restrict__ sdb,
    const int* __restrict__ counts, const int* __restrict__ bases,
    float* __restrict__ out, float* __restrict__ y) {
  int z = blockIdx.z;
  int m0 = blockIdx.y * 256, n0 = blockIdx.x * 256;
  bool sh = (z == NE);
  int count, base;
  const __bf16 *B, *A;
  if (sh) {
    count = NT; base = 0; B = sdb; A = hs;
  } else {
    count = counts[z];
    if (m0 >= count) return;
    base = bases[z];
    B = wdb + (size_t)z * (H_DIM * I_DIM);
    A = hr + (size_t)base * I_DIM;
  }

  __shared__ bf16x8 lds[8192];              // 128 KB
  bf16x8* sA = lds;                         // [2][2048]
  bf16x8* sB = lds + 4096;                  // [2][2048]

  int tid = threadIdx.x, lane = tid & 63, w = tid >> 6;
  int wm = w >> 2, wn = w & 3;
  int fr = lane & 15, fs = lane >> 4;

  int srcA[4], srcB[4];
#pragma unroll
  for (int q = 0; q < 4; q++) {
    int c = q * 512 + tid;
    int r = c >> 3, j = (c & 7) ^ (r & 7);
    int ra = m0 + r; if (ra >= count) ra = count - 1;
    srcA[q] = ra * (I_DIM / 8) + j;
    srcB[q] = (n0 + r) * (I_DIM / 8) + j;
  }

  const bf16x8* a8 = (const bf16x8*)A;
  const bf16x8* b8 = (const bf16x8*)B;

  f32x4 acc[8][4];
#pragma unroll
  for (int m = 0; m < 8; m++)
#pragma unroll
    for (int n = 0; n < 4; n++) acc[m][n] = (f32x4){0.f, 0.f, 0.f, 0.f};

  // prologue
#pragma unroll
  for (int q = 0; q < 4; q++) {
    gl16(a8 + srcA[q], sA + q * 512 + w * 64);
    gl16(b8 + srcB[q], sB + q * 512 + w * 64);
  }
  __syncthreads();

  for (int kt = 0; kt < I_DIM / 64; ++kt) {
    int cur = kt & 1, nxt = cur ^ 1;
    const bf16x8* Ac = sA + cur * 2048;
    const bf16x8* Bc = sB + cur * 2048;
    bf16x8* dA = sA + nxt * 2048;
    bf16x8* dB = sB + nxt * 2048;
    bool pf = (kt + 1 < I_DIM / 64);
    int ko = (kt + 1) * 8;

    bf16x8 bf_[4][2];
#pragma unroll
    for (int p = 0; p < 4; ++p) {
      bf16x8 af[2][2];
#pragma unroll
      for (int m2 = 0; m2 < 2; m2++)
#pragma unroll
        for (int ks = 0; ks < 2; ks++)
          af[m2][ks] = Ac[swzc(wm * 128 + (p * 2 + m2) * 16 + fr, ks * 4 + fs)];
      if (p == 0) {
#pragma unroll
        for (int n = 0; n < 4; n++)
#pragma unroll
          for (int ks = 0; ks < 2; ks++)
            bf_[n][ks] = Bc[swzc(wn * 64 + n * 16 + fr, ks * 4 + fs)];
      }
      if (pf) {
        if (p == 0) {
          gl16(a8 + srcA[0] + ko, dA + 0 * 512 + w * 64);
          gl16(a8 + srcA[1] + ko, dA + 1 * 512 + w * 64);
        } else if (p == 1) {
          gl16(a8 + srcA[2] + ko, dA + 2 * 512 + w * 64);
          gl16(a8 + srcA[3] + ko, dA + 3 * 512 + w * 64);
        } else if (p == 2) {
          gl16(b8 + srcB[0] + ko, dB + 0 * 512 + w * 64);
          gl16(b8 + srcB[1] + ko, dB + 1 * 512 + w * 64);
        } else {
          gl16(b8 + srcB[2] + ko, dB + 2 * 512 + w * 64);
          gl16(b8 + srcB[3] + ko, dB + 3 * 512 + w * 64);
        }
      }
      __builtin_amdgcn_s_setprio(1);
#pragma unroll
      for (int m2 = 0; m2 < 2; m2++)
#pragma unroll
        for (int n = 0; n < 4; n++)
#pragma unroll
          for (int ks = 0; ks < 2; ks++) {
            int m = p * 2 + m2;
            acc[m][n] = __builtin_amdgcn_mfma_f32_16x16x32_bf16(af[m2][ks], bf_[n][ks], acc[m][n], 0, 0, 0);
          }
      __builtin_amdgcn_s_setprio(0);
    }
    __syncthreads();
  }

#pragma unroll
  for (int m = 0; m < 8; m++)
#pragma unroll
    for (int n = 0; n < 4; n++)
#pragma unroll
      for (int q2 = 0; q2 < 4; q2++) {
        int row = wm * 128 + m * 16 + fs * 4 + q2;
        int col = n0 + wn * 64 + n * 16 + fr;
        float v = acc[m][n][q2];
        int grow = m0 + row;
        if (sh) out[(size_t)grow * H_DIM + col] = v;
        else if (grow < count) y[(size_t)(base + grow) * H_DIM + col] = v;
      }
}

__global__ __launch_bounds__(256) void k_combine(
    const float* __restrict__ y, const int* __restrict__ bases,
    const int* __restrict__ tE, const int* __restrict__ tP,
    const float* __restrict__ tG, float* __restrict__ out) {
  int t = blockIdx.x;
  int c = threadIdx.x;  // H/4 = 256 float4 per token row
  int e0 = tE[t * 2], e1 = tE[t * 2 + 1];
  int r0 = bases[e0] + tP[t * 2], r1 = bases[e1] + tP[t * 2 + 1];
  float g0 = tG[t * 2], g1 = tG[t * 2 + 1];
  const float4* y4 = (const float4*)y;
  float4* o4 = (float4*)out;
  float4 s = o4[(size_t)t * (H_DIM / 4) + c];
  float4 a = y4[(size_t)r0 * (H_DIM / 4) + c];
  float4 b = y4[(size_t)r1 * (H_DIM / 4) + c];
  s.x += g0 * a.x + g1 * b.x;
  s.y += g0 * a.y + g1 * b.y;
  s.z += g0 * a.z + g1 * b.z;
  s.w += g0 * a.w + g1 * b.w;
  o4[(size_t)t * (H_DIM / 4) + c] = s;
}

extern "C" void kernel_launch(void* const* d_in, const int* in_sizes, int n_in,
                              void* d_out, int out_size, void* d_ws, size_t ws_size,
                              hipStream_t stream) {
  const float* x = (const float*)d_in[0];
  const float* sg_w = (const float*)d_in[1];
  const float* su_w = (const float*)d_in[2];
  const float* sd_w = (const float*)d_in[3];
  const float* router_w = (const float*)d_in[4];
  const float* routing_bias = (const float*)d_in[5];
  const float* wg = (const float*)d_in[6];
  const float* wu = (const float*)d_in[7];
  const float* wd = (const float*)d_in[8];
  float* out = (float*)d_out;
  char* ws = (char*)d_ws;

  __bf16* xb  = (__bf16*)(ws + 0);            //  8,388,608
  __bf16* hs  = (__bf16*)(ws + 8388608);      // 16,777,216
  __bf16* hr  = (__bf16*)(ws + 25165824);     // 33,554,432
  float*  y   = (float*)(ws + 58720256);      // 33,554,432
  __bf16* wgb = (__bf16*)(ws + 92274688);     // 33,554,432
  __bf16* wub = (__bf16*)(ws + 125829120);    // 33,554,432
  __bf16* wdb = (__bf16*)(ws + 159383552);    // 33,554,432
  __bf16* sgb = (__bf16*)(ws + 192937984);    //  4,194,304
  __bf16* sub = (__bf16*)(ws + 197132288);    //  4,194,304
  __bf16* sdb = (__bf16*)(ws + 201326592);    //  4,194,304
  int* counts = (int*)(ws + 205520896);
  int* bases  = (int*)(ws + 205520928);
  int* list   = (int*)(ws + 205520960);       // 131,072
  int* tE     = (int*)(ws + 205652032);       // 32,768
  int* tP     = (int*)(ws + 205684800);       // 32,768
  float* tG   = (float*)(ws + 205717568);     // 32,768

  hipMemsetAsync(counts, 0, NE * sizeof(int), stream);
  // all-weight cast: (3*2^21 + 3*2^18) chunks / 256 = 27648 blocks
  k_castall<<<27648, 256, 0, stream>>>(wg, wu, wd, sg_w, su_w, sd_w,
                                       wgb, wub, wdb, sgb, sub, sdb);
  k_router<<<NT / 4, 256, 0, stream>>>(x, router_w, routing_bias, xb,
                                       counts, list, tE, tP, tG);
  k_prefix<<<1, 64, 0, stream>>>(counts, bases);
  dim3 gu(I_DIM / 128, NT / 256, NE + 1);
  k_upgate8<<<gu, 512, 0, stream>>>(xb, wgb, wub, sgb, sub, counts, bases, list, hs, hr);
  dim3 gd(H_DIM / 256, NT / 256, NE + 1);
  k_down8<<<gd, 512, 0, stream>>>(hs, hr, wdb, sdb, counts, bases, out, y);
  k_combine<<<NT, 256, 0, stream>>>(y, bases, tE, tP, tG, out);
}

// Round 4
// 418.609 us; speedup vs baseline: 1.1396x; 1.0082x over previous
//
#include <hip/hip_runtime.h>
#include <hip/hip_bf16.h>

#define H_DIM 1024
#define I_DIM 2048
#define NE 8
#define NT 4096

typedef __bf16 bf16x8 __attribute__((ext_vector_type(8)));
typedef __bf16 bf16x4 __attribute__((ext_vector_type(4)));
typedef float f32x4 __attribute__((ext_vector_type(4)));

// async global->LDS, 16B per lane. LDS dest is wave-uniform base (HW adds lane*16).
__device__ __forceinline__ void gl16(const void* g, void* l) {
  __builtin_amdgcn_global_load_lds(
      (const __attribute__((address_space(1))) unsigned int*)g,
      (__attribute__((address_space(3))) unsigned int*)l, 16, 0, 0);
}

// Paired LDS chunk map for a [rows][4-chunk] BK=32 sub-tile: two logical rows
// share one 8-chunk (128B) LDS row; XOR by LDS-row keeps ds_read_b128 of a
// 16-row fragment column 2-way bank-aliased (free).
__device__ __forceinline__ int lmap(int r, int j) {
  int R = r >> 1;
  return R * 8 + ((((r & 1) << 2) | j) ^ (R & 7));
}

__device__ __forceinline__ bf16x8 cvt8(float4 a, float4 b) {
  bf16x8 r;
  r[0] = (__bf16)a.x; r[1] = (__bf16)a.y; r[2] = (__bf16)a.z; r[3] = (__bf16)a.w;
  r[4] = (__bf16)b.x; r[5] = (__bf16)b.y; r[6] = (__bf16)b.z; r[7] = (__bf16)b.w;
  return r;
}

// One-shot cast of all six weight matrices fp32->bf16 (pow2 region sizes).
__global__ __launch_bounds__(256) void k_castall(
    const float* __restrict__ wg, const float* __restrict__ wu,
    const float* __restrict__ wd, const float* __restrict__ sg,
    const float* __restrict__ su, const float* __restrict__ sd,
    __bf16* __restrict__ wgb, __bf16* __restrict__ wub, __bf16* __restrict__ wdb,
    __bf16* __restrict__ sgb, __bf16* __restrict__ sub, __bf16* __restrict__ sdb) {
  long long i = (long long)blockIdx.x * 256 + threadIdx.x;
  const long long NW = 1LL << 21, NS = 1LL << 18;
  const float* s; __bf16* d; int off;
  if (i < 3 * NW) {
    int r = (int)(i >> 21); off = (int)(i & (NW - 1));
    s = (r == 0) ? wg : (r == 1) ? wu : wd;
    d = (r == 0) ? wgb : (r == 1) ? wub : wdb;
  } else {
    long long j = i - 3 * NW;
    int r = (int)(j >> 18); off = (int)(j & (NS - 1));
    s = (r == 0) ? sg : (r == 1) ? su : sd;
    d = (r == 0) ? sgb : (r == 1) ? sub : sdb;
  }
  const float4* s4 = (const float4*)s;
  float4 a = s4[(size_t)off * 2], b = s4[(size_t)off * 2 + 1];
  ((bf16x8*)d)[off] = cvt8(a, b);
}

// Router: sigmoid top-2 renorm + per-expert token lists; fuses x -> bf16 cast.
__global__ __launch_bounds__(256) void k_router(const float* __restrict__ x,
                                                const float* __restrict__ rw,
                                                const float* __restrict__ rbias,
                                                __bf16* __restrict__ xb,
                                                int* __restrict__ counts,
                                                int* __restrict__ list,
                                                int* __restrict__ tE,
                                                int* __restrict__ tP,
                                                float* __restrict__ tG) {
  int wv = threadIdx.x >> 6, lane = threadIdx.x & 63;
  int t = blockIdx.x * 4 + wv;
  float acc[NE];
#pragma unroll
  for (int e = 0; e < NE; e++) acc[e] = 0.f;
  const float4* xr = (const float4*)(x + (size_t)t * H_DIM);
  const float4* wr4 = (const float4*)rw;
  bf16x4* xo = (bf16x4*)xb + (size_t)t * (H_DIM / 4);
#pragma unroll
  for (int it = 0; it < 4; ++it) {
    int c = it * 64 + lane;
    float4 xv = xr[c];
    bf16x4 bv;
    bv[0] = (__bf16)xv.x; bv[1] = (__bf16)xv.y;
    bv[2] = (__bf16)xv.z; bv[3] = (__bf16)xv.w;
    xo[c] = bv;
#pragma unroll
    for (int e = 0; e < NE; e++) {
      float4 wv = wr4[e * (H_DIM / 4) + c];
      acc[e] += xv.x * wv.x + xv.y * wv.y + xv.z * wv.z + xv.w * wv.w;
    }
  }
#pragma unroll
  for (int e = 0; e < NE; e++) {
#pragma unroll
    for (int off = 32; off > 0; off >>= 1) acc[e] += __shfl_xor(acc[e], off, 64);
  }
  if (lane == 0) {
    float p[NE];
#pragma unroll
    for (int e = 0; e < NE; e++) p[e] = 1.f / (1.f + expf(-(acc[e] + rbias[e])));
    int e0 = 0;
#pragma unroll
    for (int e = 1; e < NE; e++) if (p[e] > p[e0]) e0 = e;
    int e1 = -1;
#pragma unroll
    for (int e = 0; e < NE; e++) if (e != e0 && (e1 < 0 || p[e] > p[e1])) e1 = e;
    float s = p[e0] + p[e1];
    float g0 = p[e0] / s, g1 = p[e1] / s;
    int p0 = atomicAdd(&counts[e0], 1);
    int p1 = atomicAdd(&counts[e1], 1);
    list[e0 * NT + p0] = t;
    list[e1 * NT + p1] = t;
    tE[t * 2] = e0; tE[t * 2 + 1] = e1;
    tP[t * 2] = p0; tP[t * 2 + 1] = p1;
    tG[t * 2] = g0; tG[t * 2 + 1] = g1;
  }
}

__global__ void k_prefix(const int* __restrict__ counts, int* __restrict__ bases) {
  if (threadIdx.x == 0) {
    int s = 0;
    for (int e = 0; e < NE; e++) { bases[e] = s; s += counts[e]; }
  }
}

// ---------------------------------------------------------------------------
// Fused gate+up GEMM. Tile 256 x 128 (g and u), 512 thr (waves 2M x 4N; wave
// = 128 rows x 32 cols of both g,u). BK=32 phases, 4-slot LDS ring, prefetch
// distance 3, counted vmcnt(8) + raw s_barrier (no drain in loop).
// ---------------------------------------------------------------------------
__global__ __launch_bounds__(512, 2) void k_upgate8(
    const __bf16* __restrict__ xb, const __bf16* __restrict__ wgb,
    const __bf16* __restrict__ wub, const __bf16* __restrict__ sgb,
    const __bf16* __restrict__ sub, const int* __restrict__ counts,
    const int* __restrict__ bases, const int* __restrict__ list,
    __bf16* __restrict__ hs, __bf16* __restrict__ hr) {
  int z = blockIdx.z;
  int m0 = blockIdx.y * 256, n0 = blockIdx.x * 128;
  bool sh = (z == NE);
  int count, base;
  const __bf16 *Bg, *Bu;
  if (sh) {
    count = NT; base = 0; Bg = sgb; Bu = sub;
  } else {
    count = counts[z];
    if (m0 >= count) return;
    base = bases[z];
    Bg = wgb + (size_t)z * (I_DIM * H_DIM);
    Bu = wub + (size_t)z * (I_DIM * H_DIM);
  }

  __shared__ bf16x8 lds[8192];              // 128 KB
  bf16x8* sA  = lds;                        // 4 slots x 1024 chunks (256r x 4c)
  bf16x8* sBg = lds + 4096;                 // 4 slots x 512  (128r x 4c)
  bf16x8* sBu = lds + 6144;

  int tid = threadIdx.x, lane = tid & 63, w = tid >> 6;
  int wm = w >> 2, wn = w & 3;
  int fr = lane & 15, fs = lane >> 4;

  // staging sources (inverse of lmap; LDS dest stays linear per wave)
  int srcA[2];
#pragma unroll
  for (int q = 0; q < 2; q++) {
    int L = q * 512 + tid;
    int R = L >> 3, cp = (L & 7) ^ (R & 7);
    int r = 2 * R + (cp >> 2), j = cp & 3;
    int gr = m0 + r;
    int tok = sh ? gr : ((gr < count) ? list[z * NT + gr] : list[z * NT]);
    srcA[q] = tok * (H_DIM / 8) + j;
  }
  int srcB;
  {
    int L = tid;
    int R = L >> 3, cp = (L & 7) ^ (R & 7);
    int r = 2 * R + (cp >> 2), j = cp & 3;
    srcB = (n0 + r) * (H_DIM / 8) + j;
  }

  // fragment LDS offsets (chunk index within slot)
  int offA[8], offB[2];
#pragma unroll
  for (int mf = 0; mf < 8; mf++) offA[mf] = lmap(wm * 128 + mf * 16 + fr, fs);
#pragma unroll
  for (int nf = 0; nf < 2; nf++) offB[nf] = lmap(wn * 32 + nf * 16 + fr, fs);

  const bf16x8* a8 = (const bf16x8*)xb;
  const bf16x8* g8 = (const bf16x8*)Bg;
  const bf16x8* u8 = (const bf16x8*)Bu;

  f32x4 accg[8][2], accu[8][2];
#pragma unroll
  for (int m = 0; m < 8; m++)
#pragma unroll
    for (int n = 0; n < 2; n++) {
      accg[m][n] = (f32x4){0.f, 0.f, 0.f, 0.f};
      accu[m][n] = (f32x4){0.f, 0.f, 0.f, 0.f};
    }

  const int NS = H_DIM / 32;  // 32 phases
  // prologue: stage sub-tiles 0..2
#pragma unroll
  for (int s = 0; s < 3; s++) {
    gl16(a8 + srcA[0] + s * 4, sA + s * 1024 + w * 64);
    gl16(a8 + srcA[1] + s * 4, sA + s * 1024 + 512 + w * 64);
    gl16(g8 + srcB + s * 4, sBg + s * 512 + w * 64);
    gl16(u8 + srcB + s * 4, sBu + s * 512 + w * 64);
  }

#pragma unroll 4
  for (int s = 0; s < NS; ++s) {
    asm volatile("s_waitcnt vmcnt(8)" ::: "memory");   // sub-tile s landed (mine)
    __builtin_amdgcn_s_barrier();                      // everyone's landed; WAR fence
    asm volatile("" ::: "memory");
    int sp = s + 3; if (sp >= NS) sp -= NS;            // wrapped tail = junk prefetch
    int sw = (s + 3) & 3;
    gl16(a8 + srcA[0] + sp * 4, sA + sw * 1024 + w * 64);
    gl16(a8 + srcA[1] + sp * 4, sA + sw * 1024 + 512 + w * 64);
    gl16(g8 + srcB + sp * 4, sBg + sw * 512 + w * 64);
    gl16(u8 + srcB + sp * 4, sBu + sw * 512 + w * 64);
    const bf16x8* As = sA + (s & 3) * 1024;
    const bf16x8* Gs = sBg + (s & 3) * 512;
    const bf16x8* Us = sBu + (s & 3) * 512;
    bf16x8 af[8], bg[2], bu[2];
#pragma unroll
    for (int mf = 0; mf < 8; mf++) af[mf] = As[offA[mf]];
#pragma unroll
    for (int nf = 0; nf < 2; nf++) { bg[nf] = Gs[offB[nf]]; bu[nf] = Us[offB[nf]]; }
    __builtin_amdgcn_s_setprio(1);
#pragma unroll
    for (int m = 0; m < 8; m++)
#pragma unroll
      for (int n = 0; n < 2; n++) {
        accg[m][n] = __builtin_amdgcn_mfma_f32_16x16x32_bf16(af[m], bg[n], accg[m][n], 0, 0, 0);
        accu[m][n] = __builtin_amdgcn_mfma_f32_16x16x32_bf16(af[m], bu[n], accu[m][n], 0, 0, 0);
      }
    __builtin_amdgcn_s_setprio(0);
  }
  asm volatile("s_waitcnt vmcnt(0)" ::: "memory");     // settle LDS-DMA before exit

#pragma unroll
  for (int m = 0; m < 8; m++)
#pragma unroll
    for (int n = 0; n < 2; n++)
#pragma unroll
      for (int q2 = 0; q2 < 4; q2++) {
        int row = wm * 128 + m * 16 + fs * 4 + q2;
        int col = n0 + wn * 32 + n * 16 + fr;
        float g = accg[m][n][q2], u = accu[m][n][q2];
        float h = g * u / (1.f + expf(-g));  // silu(g)*u
        __bf16 hb = (__bf16)h;
        int grow = m0 + row;
        if (sh) hs[(size_t)grow * I_DIM + col] = hb;
        else if (grow < count) hr[(size_t)(base + grow) * I_DIM + col] = hb;
      }
}

// Down GEMM. Tile 256 x 256, same ring pipeline (wave = 128 rows x 64 cols).
__global__ __launch_bounds__(512, 2) void k_down8(
    const __bf16* __restrict__ hs, const __bf16* __restrict__ hr,
    const __bf16* __restrict__ wdb, const __bf16* __restrict__ sdb,
    const int* __restrict__ counts, const int* __restrict__ bases,
    float* __restrict__ out, float* __restrict__ y) {
  int z = blockIdx.z;
  int m0 = blockIdx.y * 256, n0 = blockIdx.x * 256;
  bool sh = (z == NE);
  int count, base;
  const __bf16 *B, *A;
  if (sh) {
    count = NT; base = 0; B = sdb; A = hs;
  } else {
    count = counts[z];
    if (m0 >= count) return;
    base = bases[z];
    B = wdb + (size_t)z * (H_DIM * I_DIM);
    A = hr + (size_t)base * I_DIM;
  }

  __shared__ bf16x8 lds[8192];              // 128 KB
  bf16x8* sA = lds;                         // 4 slots x 1024
  bf16x8* sB = lds + 4096;                  // 4 slots x 1024

  int tid = threadIdx.x, lane = tid & 63, w = tid >> 6;
  int wm = w >> 2, wn = w & 3;
  int fr = lane & 15, fs = lane >> 4;

  int srcA[2], srcB[2];
#pragma unroll
  for (int q = 0; q < 2; q++) {
    int L = q * 512 + tid;
    int R = L >> 3, cp = (L & 7) ^ (R & 7);
    int r = 2 * R + (cp >> 2), j = cp & 3;
    int ra = m0 + r; if (ra >= count) ra = count - 1;
    srcA[q] = ra * (I_DIM / 8) + j;
    srcB[q] = (n0 + r) * (I_DIM / 8) + j;
  }

  int offA[8], offB[4];
#pragma unroll
  for (int mf = 0; mf < 8; mf++) offA[mf] = lmap(wm * 128 + mf * 16 + fr, fs);
#pragma unroll
  for (int nf = 0; nf < 4; nf++) offB[nf] = lmap(wn * 64 + nf * 16 + fr, fs);

  const bf16x8* a8 = (const bf16x8*)A;
  const bf16x8* b8 = (const bf16x8*)B;

  f32x4 acc[8][4];
#pragma unroll
  for (int m = 0; m < 8; m++)
#pragma unroll
    for (int n = 0; n < 4; n++) acc[m][n] = (f32x4){0.f, 0.f, 0.f, 0.f};

  const int NS = I_DIM / 32;  // 64 phases
#pragma unroll
  for (int s = 0; s < 3; s++) {
    gl16(a8 + srcA[0] + s * 4, sA + s * 1024 + w * 64);
    gl16(a8 + srcA[1] + s * 4, sA + s * 1024 + 512 + w * 64);
    gl16(b8 + srcB[0] + s * 4, sB + s * 1024 + w * 64);
    gl16(b8 + srcB[1] + s * 4, sB + s * 1024 + 512 + w * 64);
  }

#pragma unroll 4
  for (int s = 0; s < NS; ++s) {
    asm volatile("s_waitcnt vmcnt(8)" ::: "memory");
    __builtin_amdgcn_s_barrier();
    asm volatile("" ::: "memory");
    int sp = s + 3; if (sp >= NS) sp -= NS;
    int sw = (s + 3) & 3;
    gl16(a8 + srcA[0] + sp * 4, sA + sw * 1024 + w * 64);
    gl16(a8 + srcA[1] + sp * 4, sA + sw * 1024 + 512 + w * 64);
    gl16(b8 + srcB[0] + sp * 4, sB + sw * 1024 + w * 64);
    gl16(b8 + srcB[1] + sp * 4, sB + sw * 1024 + 512 + w * 64);
    const bf16x8* As = sA + (s & 3) * 1024;
    const bf16x8* Bs = sB + (s & 3) * 1024;
    bf16x8 af[8], bf_[4];
#pragma unroll
    for (int mf = 0; mf < 8; mf++) af[mf] = As[offA[mf]];
#pragma unroll
    for (int nf = 0; nf < 4; nf++) bf_[nf] = Bs[offB[nf]];
    __builtin_amdgcn_s_setprio(1);
#pragma unroll
    for (int m = 0; m < 8; m++)
#pragma unroll
      for (int n = 0; n < 4; n++)
        acc[m][n] = __builtin_amdgcn_mfma_f32_16x16x32_bf16(af[m], bf_[n], acc[m][n], 0, 0, 0);
    __builtin_amdgcn_s_setprio(0);
  }
  asm volatile("s_waitcnt vmcnt(0)" ::: "memory");

#pragma unroll
  for (int m = 0; m < 8; m++)
#pragma unroll
    for (int n = 0; n < 4; n++)
#pragma unroll
      for (int q2 = 0; q2 < 4; q2++) {
        int row = wm * 128 + m * 16 + fs * 4 + q2;
        int col = n0 + wn * 64 + n * 16 + fr;
        float v = acc[m][n][q2];
        int grow = m0 + row;
        if (sh) out[(size_t)grow * H_DIM + col] = v;
        else if (grow < count) y[(size_t)(base + grow) * H_DIM + col] = v;
      }
}

__global__ __launch_bounds__(256) void k_combine(
    const float* __restrict__ y, const int* __restrict__ bases,
    const int* __restrict__ tE, const int* __restrict__ tP,
    const float* __restrict__ tG, float* __restrict__ out) {
  int t = blockIdx.x;
  int c = threadIdx.x;  // H/4 = 256 float4 per token row
  int e0 = tE[t * 2], e1 = tE[t * 2 + 1];
  int r0 = bases[e0] + tP[t * 2], r1 = bases[e1] + tP[t * 2 + 1];
  float g0 = tG[t * 2], g1 = tG[t * 2 + 1];
  const float4* y4 = (const float4*)y;
  float4* o4 = (float4*)out;
  float4 s = o4[(size_t)t * (H_DIM / 4) + c];
  float4 a = y4[(size_t)r0 * (H_DIM / 4) + c];
  float4 b = y4[(size_t)r1 * (H_DIM / 4) + c];
  s.x += g0 * a.x + g1 * b.x;
  s.y += g0 * a.y + g1 * b.y;
  s.z += g0 * a.z + g1 * b.z;
  s.w += g0 * a.w + g1 * b.w;
  o4[(size_t)t * (H_DIM / 4) + c] = s;
}

extern "C" void kernel_launch(void* const* d_in, const int* in_sizes, int n_in,
                              void* d_out, int out_size, void* d_ws, size_t ws_size,
                              hipStream_t stream) {
  const float* x = (const float*)d_in[0];
  const float* sg_w = (const float*)d_in[1];
  const float* su_w = (const float*)d_in[2];
  const float* sd_w = (const float*)d_in[3];
  const float* router_w = (const float*)d_in[4];
  const float* routing_bias = (const float*)d_in[5];
  const float* wg = (const float*)d_in[6];
  const float* wu = (const float*)d_in[7];
  const float* wd = (const float*)d_in[8];
  float* out = (float*)d_out;
  char* ws = (char*)d_ws;

  __bf16* xb  = (__bf16*)(ws + 0);            //  8,388,608
  __bf16* hs  = (__bf16*)(ws + 8388608);      // 16,777,216
  __bf16* hr  = (__bf16*)(ws + 25165824);     // 33,554,432
  float*  y   = (float*)(ws + 58720256);      // 33,554,432
  __bf16* wgb = (__bf16*)(ws + 92274688);     // 33,554,432
  __bf16* wub = (__bf16*)(ws + 125829120);    // 33,554,432
  __bf16* wdb = (__bf16*)(ws + 159383552);    // 33,554,432
  __bf16* sgb = (__bf16*)(ws + 192937984);    //  4,194,304
  __bf16* sub = (__bf16*)(ws + 197132288);    //  4,194,304
  __bf16* sdb = (__bf16*)(ws + 201326592);    //  4,194,304
  int* counts = (int*)(ws + 205520896);
  int* bases  = (int*)(ws + 205520928);
  int* list   = (int*)(ws + 205520960);       // 131,072
  int* tE     = (int*)(ws + 205652032);       // 32,768
  int* tP     = (int*)(ws + 205684800);       // 32,768
  float* tG   = (float*)(ws + 205717568);     // 32,768

  hipMemsetAsync(counts, 0, NE * sizeof(int), stream);
  k_castall<<<27648, 256, 0, stream>>>(wg, wu, wd, sg_w, su_w, sd_w,
                                       wgb, wub, wdb, sgb, sub, sdb);
  k_router<<<NT / 4, 256, 0, stream>>>(x, router_w, routing_bias, xb,
                                       counts, list, tE, tP, tG);
  k_prefix<<<1, 64, 0, stream>>>(counts, bases);
  dim3 gu(I_DIM / 128, NT / 256, NE + 1);
  k_upgate8<<<gu, 512, 0, stream>>>(xb, wgb, wub, sgb, sub, counts, bases, list, hs, hr);
  dim3 gd(H_DIM / 256, NT / 256, NE + 1);
  k_down8<<<gd, 512, 0, stream>>>(hs, hr, wdb, sdb, counts, bases, out, y);
  k_combine<<<NT, 256, 0, stream>>>(y, bases, tE, tP, tG, out);
}